// Round 10
// baseline (103.525 us; speedup 1.0000x reference)
//
#include <hip/hip_runtime.h>

// z: [32,64,32,32] fp32, codebook: [1024,64] fp32
#define C_DIM   64
#define K_CODES 1024
#define HW      1024
#define CHW     (C_DIM * HW)             // 65536
#define N_TOTAL 32768
#define CODES_ELEMS 2097152

#define THREADS 256                      // 4 waves; wave w == ktl (k partition)
#define NBLK    32                       // one 32-n tile per block
#define NGROUPS 8                        // per wave: kt = g*4 + ktl

typedef _Float16 half8  __attribute__((ext_vector_type(8)));
typedef float    f32x16 __attribute__((ext_vector_type(16)));

#define WS_A_ELEMS 16384                 // half8 count: 256 KB A-frags
#define XPAD 68                          // fp32 row pitch: 16B-aligned, bank-rotating

__device__ __forceinline__ bool better(float k1, int i1, float k2, int i2) {
    return (k1 > k2) || (k1 == k2 && i1 < i2);
}
__device__ __forceinline__ void merge2(float& bk, int& bi, float& sk, int& si,
                                       float obk, int obi, float osk, int osi) {
    if (better(obk, obi, bk, bi)) {
        float nsk; int nsi;
        if (better(bk, bi, osk, osi)) { nsk = bk; nsi = bi; } else { nsk = osk; nsi = osi; }
        bk = obk; bi = obi; sk = nsk; si = nsi;
    } else {
        if (better(obk, obi, sk, si)) { sk = obk; si = obi; }
    }
}

// One-shot prep: blocks 0..31 -> hi/lo fp16 A-fragment layout; block 32 -> cnorm.
__global__ void prep_kernel(const float* __restrict__ cb, half8* __restrict__ wsA,
                            float* __restrict__ wsCn) {
    if (blockIdx.x < 32) {
        const int tid = blockIdx.x * 256 + threadIdx.x;   // 0..8191
        const int kt = tid >> 8, q = (tid >> 6) & 3, l = tid & 63;
        const int k  = kt * 32 + (l & 31);
        const int c0 = q * 16 + (l >> 5) * 8;
        const float4* p = (const float4*)(cb + k * C_DIM + c0);
        float4 f0 = p[0], f1 = p[1];
        float v[8] = {f0.x,f0.y,f0.z,f0.w,f1.x,f1.y,f1.z,f1.w};
        half8 h8, l8;
#pragma unroll
        for (int j = 0; j < 8; ++j) {
            _Float16 hh = (_Float16)v[j];
            _Float16 ll = (_Float16)(v[j] - (float)hh);
            h8[j] = hh; l8[j] = ll;
        }
        wsA[((kt * 4 + q) * 2 + 0) * 64 + l] = h8;
        wsA[((kt * 4 + q) * 2 + 1) * 64 + l] = l8;
    } else {
#pragma unroll
        for (int rep = 0; rep < 4; ++rep) {
            const int k = threadIdx.x * 4 + rep;
            const float4* row = (const float4*)(cb + k * C_DIM);
            float r[8];
            {
                float4 f0 = row[0], f1 = row[1];
                float v[8] = {f0.x,f0.y,f0.z,f0.w,f1.x,f1.y,f1.z,f1.w};
#pragma unroll
                for (int j = 0; j < 8; ++j) r[j] = v[j]*v[j];
            }
#pragma unroll
            for (int i = 2; i < 16; i += 2) {
                float4 f0 = row[i], f1 = row[i+1];
                float v[8] = {f0.x,f0.y,f0.z,f0.w,f1.x,f1.y,f1.z,f1.w};
#pragma unroll
                for (int j = 0; j < 8; ++j) r[j] = fmaf(v[j], v[j], r[j]);
            }
            wsCn[k] = ((r[0]+r[1])+(r[2]+r[3])) + ((r[4]+r[5])+(r[6]+r[7]));
        }
    }
}

__launch_bounds__(THREADS)
__global__ void vq_kernel(const float* __restrict__ z, const float* __restrict__ cb,
                          const half8* __restrict__ wsA, const float* __restrict__ wsCn,
                          float* __restrict__ out) {
    __shared__ float sX[NBLK][XPAD];     // fp32 x tile (single z read; feeds B-build + refine)
    __shared__ half8 sB[4][2][64];       // B-frags hi/lo (8 KB)
    __shared__ float sCn[K_CODES];       // 4 KB
    __shared__ float sRed[4][32][4];     // [ktl][col][bk,bi,sk,si]
    __shared__ int   sCandA[NBLK], sCandB[NBLK], sIdxF[NBLK];

    const int t    = threadIdx.x;
    const int lane = t & 63;
    const int ktl  = t >> 6;             // wave id == k partition
    const int base_n  = blockIdx.x * NBLK;
    const int bb      = base_n >> 10;    // NBLK=32 divides HW -> b constant per block
    const int base_hw = base_n & 1023;

    // ---- Stage x into LDS: thread (c = t>>2, i = t&3) reads 8 consecutive hw
    // floats (fully coalesced 128B segments), writes sX[n][c].
    {
        const int c = t >> 2, i = t & 3;
        const float4* p = (const float4*)(z + bb * CHW + c * HW + base_hw + i * 8);
        float4 f0 = p[0], f1 = p[1];
        float v[8] = {f0.x,f0.y,f0.z,f0.w,f1.x,f1.y,f1.z,f1.w};
#pragma unroll
        for (int j = 0; j < 8; ++j) sX[i * 8 + j][c] = v[j];
    }
    ((float4*)sCn)[t] = ((const float4*)wsCn)[t];   // cnorm -> LDS
    __syncthreads();

    // ---- Build B-frags from sX: thread (q = t>>6, l = t&63) -> both hi/lo.
    {
        const int q = t >> 6, l = t & 63;
        const float* xp = &sX[l & 31][q * 16 + (l >> 5) * 8];
        float4 f0 = *(const float4*)xp;
        float4 f1 = *(const float4*)(xp + 4);
        float v[8] = {f0.x,f0.y,f0.z,f0.w,f1.x,f1.y,f1.z,f1.w};
        half8 h8, l8;
#pragma unroll
        for (int j = 0; j < 8; ++j) {
            _Float16 hh = (_Float16)v[j];
            _Float16 ll = (_Float16)(v[j] - (float)hh);
            h8[j] = hh; l8[j] = ll;
        }
        sB[q][0][l] = h8;
        sB[q][1][l] = l8;
    }
    __syncthreads();

    // ---- k-loop: per wave 8 groups of one 32-k tile. Low live set (<64 VGPR):
    // acc 16 + a/b transient 16 + scan 12. A coalesced from ws (L2), B from LDS.
    float bk0 = -3.4e38f, sk0 = -3.4e38f; int bi0 = 0, si0 = 0;
    float bk1 = -3.4e38f, sk1 = -3.4e38f; int bi1 = 0, si1 = 0;

#pragma unroll
    for (int g = 0; g < NGROUPS; ++g) {
        const int kt = g * 4 + ktl;
        f32x16 acc;                       // init = -cn/2 (exact fp32 fold)
#pragma unroll
        for (int q = 0; q < 4; ++q) {
            float4 cq = *(const float4*)(sCn + kt * 32 + 8 * q + 4 * (lane >> 5));
            acc[4*q+0] = -0.5f * cq.x;
            acc[4*q+1] = -0.5f * cq.y;
            acc[4*q+2] = -0.5f * cq.z;
            acc[4*q+3] = -0.5f * cq.w;
        }
#pragma unroll
        for (int q = 0; q < 4; ++q) {
            half8 ah = wsA[((kt * 4 + q) * 2 + 0) * 64 + lane];
            half8 al = wsA[((kt * 4 + q) * 2 + 1) * 64 + lane];
            half8 bh = sB[q][0][lane];
            half8 bl = sB[q][1][lane];
            acc = __builtin_amdgcn_mfma_f32_32x32x16_f16(ah, bh, acc, 0, 0, 0);
            acc = __builtin_amdgcn_mfma_f32_32x32x16_f16(al, bh, acc, 0, 0, 0);
            acc = __builtin_amdgcn_mfma_f32_32x32x16_f16(ah, bl, acc, 0, 0, 0);
        }

        const int kbase = kt * 32 + 4 * (lane >> 5);
#pragma unroll
        for (int r = 0; r < 8; ++r) {
            float v = acc[r];
            int ki = kbase + (r & 3) + 8 * (r >> 2);
            if (v > bk0)      { sk0 = bk0; si0 = bi0; bk0 = v; bi0 = ki; }
            else if (v > sk0) { sk0 = v; si0 = ki; }
        }
#pragma unroll
        for (int r = 8; r < 16; ++r) {
            float v = acc[r];
            int ki = kbase + (r & 3) + 8 * (r >> 2);
            if (v > bk1)      { sk1 = bk1; si1 = bi1; bk1 = v; bi1 = ki; }
            else if (v > sk1) { sk1 = v; si1 = ki; }
        }
    }

    // ---- merge chains, then lane halves (l vs l+32: same n, complementary rows)
    float bk = bk0, sk = sk0; int bi = bi0, si = si0;
    merge2(bk, bi, sk, si, bk1, bi1, sk1, si1);
    {
        float obk = __shfl_xor(bk, 32, 64); int obi = __shfl_xor(bi, 32, 64);
        float osk = __shfl_xor(sk, 32, 64); int osi = __shfl_xor(si, 32, 64);
        merge2(bk, bi, sk, si, obk, obi, osk, osi);
    }
    if (lane < 32) {
        sRed[ktl][lane][0] = bk;
        sRed[ktl][lane][1] = __int_as_float(bi);
        sRed[ktl][lane][2] = sk;
        sRed[ktl][lane][3] = __int_as_float(si);
    }
    __syncthreads();

    // ---- cross-partition merge (index tiebreak is on true k, partition order free)
    if (t < NBLK) {
        float fbk = sRed[0][t][0]; int fbi = __float_as_int(sRed[0][t][1]);
        float fsk = sRed[0][t][2]; int fsi = __float_as_int(sRed[0][t][3]);
#pragma unroll
        for (int p = 1; p < 4; ++p)
            merge2(fbk, fbi, fsk, fsi,
                   sRed[p][t][0], __float_as_int(sRed[p][t][1]),
                   sRed[p][t][2], __float_as_int(sRed[p][t][3]));
        sCandA[t] = fbi;
        sCandB[t] = fsi;
    }
    __syncthreads();

    // ---- cooperative exact refinement: 8 lanes per n, x from LDS; xnorm cancels.
    {
        const int n_l = t >> 3, j = t & 7;
        const int c0i = sCandA[n_l], c1i = sCandB[n_l];
        const float* xp = &sX[n_l][j * 8];
        float4 x0 = *(const float4*)xp;
        float4 x1 = *(const float4*)(xp + 4);
        float xv[8] = {x0.x,x0.y,x0.z,x0.w,x1.x,x1.y,x1.z,x1.w};
        const float4* r0 = (const float4*)(cb + c0i * C_DIM + j * 8);
        const float4* r1 = (const float4*)(cb + c1i * C_DIM + j * 8);
        float4 a0 = r0[0], a1 = r0[1], b0 = r1[0], b1 = r1[1];
        float q0[8] = {a0.x,a0.y,a0.z,a0.w,a1.x,a1.y,a1.z,a1.w};
        float q1[8] = {b0.x,b0.y,b0.z,b0.w,b1.x,b1.y,b1.z,b1.w};
        float p0 = 0.f, p1 = 0.f;
#pragma unroll
        for (int i = 0; i < 8; ++i) {
            p0 = fmaf(xv[i], q0[i], p0);
            p1 = fmaf(xv[i], q1[i], p1);
        }
        p0 += __shfl_xor(p0, 1, 64); p0 += __shfl_xor(p0, 2, 64); p0 += __shfl_xor(p0, 4, 64);
        p1 += __shfl_xor(p1, 1, 64); p1 += __shfl_xor(p1, 2, 64); p1 += __shfl_xor(p1, 4, 64);
        if (j == 0) {
            float k0 = fmaf(-2.f, p0, sCn[c0i]);   // d - xnorm (xnorm cancels)
            float k1 = fmaf(-2.f, p1, sCn[c1i]);
            int win = (k1 < k0 || (k1 == k0 && c1i < c0i)) ? c1i : c0i;
            sIdxF[n_l] = win;
            out[CODES_ELEMS + base_n + n_l] = (float)win;
        }
    }
    __syncthreads();

    // ---- cooperative codes write: thread (n, chunk) reads 8 contiguous row
    // floats (L2-hot) and writes 8 column-strided floats.
    {
        const int n_l = t >> 3, j = t & 7;
        const int idx = sIdxF[n_l];
        const float4* rp = (const float4*)(cb + idx * C_DIM + j * 8);
        float4 f0 = rp[0], f1 = rp[1];
        float vv[8] = {f0.x,f0.y,f0.z,f0.w,f1.x,f1.y,f1.z,f1.w};
        float* op = out + bb * CHW + base_hw + n_l;
#pragma unroll
        for (int i = 0; i < 8; ++i) op[(j * 8 + i) * HW] = vv[i];
    }
}

extern "C" void kernel_launch(void* const* d_in, const int* in_sizes, int n_in,
                              void* d_out, int out_size, void* d_ws, size_t ws_size,
                              hipStream_t stream) {
    const float* z  = (const float*)d_in[0];
    const float* cb = (const float*)d_in[1];
    float* out = (float*)d_out;
    half8* wsA  = (half8*)d_ws;
    float* wsCn = (float*)((char*)d_ws + WS_A_ELEMS * sizeof(half8));

    prep_kernel<<<33, 256, 0, stream>>>(cb, wsA, wsCn);
    vq_kernel<<<N_TOTAL / NBLK, THREADS, 0, stream>>>(z, cb, wsA, wsCn, out);
}